// Round 1
// baseline (1994.235 us; speedup 1.0000x reference)
//
#include <hip/hip_runtime.h>
#include <hip/hip_fp16.h>
#include <stdint.h>

// SNNClassifier: B=16384, F=256, H=256, C=10, T=100
// Phase 1: layer-1 LIF spikes depend only on x[b,f] -> precompute 100-step
//          spike bitmask into d_ws (100 x 16384 x 256 bits = 52.4 MB).
// Phase 2: persistent-state fused kernel: per t, h = Z(t) @ W^T via f16
//          split-2 MFMA (W = Whi + 2^-11 * Wlo', exact 0/1 A operand),
//          then bit-exact-vs-numpy LIF update (no FMA contraction), spike
//          count accumulated in registers; epilogue does the readout GEMM
//          via shfl reduction + atomicAdd.

#define BB 16384
#define FF 256
#define HH 256
#define CC 10
#define TT 100

typedef __attribute__((ext_vector_type(8))) _Float16 half8;
typedef __attribute__((ext_vector_type(4))) float f32x4;

// ---------------- kernel 1: layer-1 spike bitmask ----------------
// wave = (b, 64-wide f segment); __ballot packs 64 spikes/step.
__global__ void spike_gen(const float* __restrict__ x,
                          unsigned long long* __restrict__ Z) {
  const int gw   = (int)((blockIdx.x * blockDim.x + threadIdx.x) >> 6);
  const int lane = threadIdx.x & 63;
  const int b    = gw >> 2;
  const int seg  = gw & 3;
  const float K_VM = (float)(0.001 * 100.0);        // 0.1f, numpy-exact
  const float K_ID = (float)(1.0 - 0.001 * 200.0);  // 0.8f, numpy-exact
  const float xv = x[b * FF + seg * 64 + lane];
  float v = 0.0f, cur = 0.0f;
  unsigned long long* zp = Z + (size_t)b * 4 + seg;
  for (int t = 0; t < TT; ++t) {
    // v_dec = v + 0.1f*((0-v)+i); i_dec = i*0.8f;  (separate roundings!)
    float vd   = __fadd_rn(v, __fmul_rn(K_VM, __fadd_rn(-v, cur)));
    float idec = __fmul_rn(cur, K_ID);
    bool z = (vd > 1.0f);  // == (vd - 1.0f) > 0
    unsigned long long m = __ballot(z);
    if (lane == 0) zp[(size_t)t * (BB * 4)] = m;
    v = z ? 0.0f : vd;
    cur = __fadd_rn(idec, xv);
  }
}

// unpack 8 spike bits -> 8 f16 values (0.0 / 1.0), MFMA fragment order
__device__ __forceinline__ half8 unpack_byte_f16(uint32_t byte) {
  union { uint32_t u[4]; half8 h; } r;
#pragma unroll
  for (int p = 0; p < 4; ++p) {
    uint32_t b2 = (byte >> (2 * p)) & 3u;
    // b2*0x8001 & 0x10001 puts bit0->bit0, bit1->bit16; *0x3C00 -> f16 1.0s
    r.u[p] = ((b2 * 0x8001u) & 0x10001u) * 0x3C00u;
  }
  return r.h;
}

// ---------------- kernel 2: fused temporal loop ----------------
// grid: (B/64) b-chunks x 4 h-chunks. block=256 (4 waves).
// wave tile: 16 b-rows x 64 h-cols, 4 timestep-planes per group.
__global__ __launch_bounds__(256, 2) void snn_main(
    const uint32_t* __restrict__ Z, const float* __restrict__ Wh,
    const float* __restrict__ bh, const float* __restrict__ Wr,
    const float* __restrict__ br, float* __restrict__ out) {
  // padded LDS copies of W rows (this block's 64 h) in split-f16
  __shared__ __align__(16) _Float16 WhiS[64][264];
  __shared__ __align__(16) _Float16 WloS[64][264];

  const int tid = threadIdx.x;
  const int bx  = blockIdx.x;
  const int hc  = bx & 3;
  const int bc  = bx >> 2;
  const int h0  = hc * 64;
  const int b0  = bc * 64;

  // ---- stage W -> LDS as (hi, lo*2048) f16 digits, denormal-guarded ----
  {
    const int r  = tid >> 2;         // 0..63 row
    const int f0 = (tid & 3) * 64;   // f segment
    const float* wrow = Wh + (size_t)(h0 + r) * FF + f0;
#pragma unroll 8
    for (int j = 0; j < 64; ++j) {
      float w = wrow[j];
      _Float16 hi = (fabsf(w) < 6.2e-5f) ? (_Float16)0.0f : (_Float16)w;
      _Float16 lo = (_Float16)((w - (float)hi) * 2048.0f);
      WhiS[r][f0 + j] = hi;
      WloS[r][f0 + j] = lo;
    }
  }
  __syncthreads();

  const int lane = tid & 63;
  const int wv   = tid >> 6;       // wave 0..3 -> b sub-tile
  const int col  = lane & 15;      // A: m-row / B: n-col / C: col
  const int quad = lane >> 4;      // k-chunk selector
  const int q8   = quad * 8;

  const int brow = b0 + wv * 16 + col;  // A-operand b row for this lane

  const float K_VM = (float)(0.001 * 100.0);
  const float K_ID = (float)(1.0 - 0.001 * 200.0);

  float v2[4][4], ii[4][4], sc[4][4];
#pragma unroll
  for (int nt = 0; nt < 4; ++nt)
#pragma unroll
    for (int r = 0; r < 4; ++r) { v2[nt][r] = 0.f; ii[nt][r] = 0.f; sc[nt][r] = 0.f; }

  float bias[4];
#pragma unroll
  for (int nt = 0; nt < 4; ++nt) bias[nt] = bh[h0 + nt * 16 + col];

  const f32x4 zero4 = {0.f, 0.f, 0.f, 0.f};

#pragma unroll 1
  for (int tg = 0; tg < TT / 4; ++tg) {
    // preload spike bits: 4 t-planes x 32B row per lane
    uint32_t zb[4][8];
#pragma unroll
    for (int j = 0; j < 4; ++j) {
      const uint32_t* p = Z + ((size_t)(tg * 4 + j) * BB + brow) * 8;
      uint4 a = *(const uint4*)p;
      uint4 bq = *(const uint4*)(p + 4);
      zb[j][0] = a.x; zb[j][1] = a.y; zb[j][2] = a.z; zb[j][3] = a.w;
      zb[j][4] = bq.x; zb[j][5] = bq.y; zb[j][6] = bq.z; zb[j][7] = bq.w;
    }

    f32x4 acc[4][4];

    // ---- phase LO: acc = Z . Wlo' ----
#pragma unroll
    for (int k = 0; k < 8; ++k) {
      half8 Bf[4];
#pragma unroll
      for (int nt = 0; nt < 4; ++nt)
        Bf[nt] = *(const half8*)&WloS[nt * 16 + col][k * 32 + q8];
#pragma unroll
      for (int j = 0; j < 4; ++j) {
        half8 Af = unpack_byte_f16((zb[j][k] >> q8) & 0xFFu);
#pragma unroll
        for (int nt = 0; nt < 4; ++nt) {
          acc[j][nt] = __builtin_amdgcn_mfma_f32_16x16x32_f16(
              Af, Bf[nt], (k == 0) ? zero4 : acc[j][nt], 0, 0, 0);
        }
      }
    }
    // exact power-of-2 rescale of lo digit
#pragma unroll
    for (int j = 0; j < 4; ++j)
#pragma unroll
      for (int nt = 0; nt < 4; ++nt)
#pragma unroll
        for (int r = 0; r < 4; ++r)
          acc[j][nt][r] = __fmul_rn(acc[j][nt][r], 4.8828125e-4f); // 2^-11

    // ---- phase HI: acc += Z . Whi ----
#pragma unroll
    for (int k = 0; k < 8; ++k) {
      half8 Bf[4];
#pragma unroll
      for (int nt = 0; nt < 4; ++nt)
        Bf[nt] = *(const half8*)&WhiS[nt * 16 + col][k * 32 + q8];
#pragma unroll
      for (int j = 0; j < 4; ++j) {
        half8 Af = unpack_byte_f16((zb[j][k] >> q8) & 0xFFu);
#pragma unroll
        for (int nt = 0; nt < 4; ++nt) {
          acc[j][nt] = __builtin_amdgcn_mfma_f32_16x16x32_f16(
              Af, Bf[nt], acc[j][nt], 0, 0, 0);
        }
      }
    }

    // ---- 4 sequential layer-2 LIF updates (numpy op order) ----
#pragma unroll
    for (int j = 0; j < 4; ++j) {
#pragma unroll
      for (int nt = 0; nt < 4; ++nt) {
#pragma unroll
        for (int r = 0; r < 4; ++r) {
          float h  = __fadd_rn(acc[j][nt][r], bias[nt]);
          float vv = v2[nt][r], ci = ii[nt][r];
          float vd   = __fadd_rn(vv, __fmul_rn(K_VM, __fadd_rn(-vv, ci)));
          float idec = __fmul_rn(ci, K_ID);
          bool z = (vd > 1.0f);
          v2[nt][r] = z ? 0.0f : vd;
          ii[nt][r] = __fadd_rn(idec, h);
          sc[nt][r] = __fadd_rn(sc[nt][r], z ? 1.0f : 0.0f);
        }
      }
    }
  }

  // ---- epilogue: readout GEMM, fused ----
  float mean[4][4];
#pragma unroll
  for (int nt = 0; nt < 4; ++nt)
#pragma unroll
    for (int r = 0; r < 4; ++r) mean[nt][r] = __fdiv_rn(sc[nt][r], 100.0f);

#pragma unroll 1
  for (int c = 0; c < CC; ++c) {
    float wc[4];
#pragma unroll
    for (int nt = 0; nt < 4; ++nt) wc[nt] = Wr[c * HH + h0 + nt * 16 + col];
#pragma unroll
    for (int r = 0; r < 4; ++r) {
      float s = 0.f;
#pragma unroll
      for (int nt = 0; nt < 4; ++nt) s = fmaf(mean[nt][r], wc[nt], s);
      s += __shfl_xor(s, 1);
      s += __shfl_xor(s, 2);
      s += __shfl_xor(s, 4);
      s += __shfl_xor(s, 8);
      if (col == 0) {
        int b = b0 + wv * 16 + quad * 4 + r;
        float add = s + ((hc == 0) ? br[c] : 0.0f);
        atomicAdd(&out[b * CC + c], add);
      }
    }
  }
}

extern "C" void kernel_launch(void* const* d_in, const int* in_sizes, int n_in,
                              void* d_out, int out_size, void* d_ws, size_t ws_size,
                              hipStream_t stream) {
  const float* x  = (const float*)d_in[0];
  const float* Wh = (const float*)d_in[1];
  const float* bh = (const float*)d_in[2];
  const float* Wr = (const float*)d_in[3];
  const float* br = (const float*)d_in[4];
  float* out = (float*)d_out;

  // workspace: spike bitmask, 100*16384*32B = 52.4 MB
  unsigned long long* Z = (unsigned long long*)d_ws;

  hipMemsetAsync(d_out, 0, (size_t)out_size * sizeof(float), stream);
  spike_gen<<<BB, 256, 0, stream>>>(x, Z);
  snn_main<<<(BB / 64) * 4, 256, 0, stream>>>((const uint32_t*)Z, Wh, bh, Wr, br, out);
}

// Round 2
// 689.907 us; speedup vs baseline: 2.8906x; 2.8906x over previous
//
#include <hip/hip_runtime.h>
#include <hip/hip_fp16.h>
#include <stdint.h>

// SNNClassifier: B=16384, F=256, H=256, C=10, T=100
// Phase 1: layer-1 LIF spikes depend only on x[b,f] -> precompute 100-step
//          spike bitmask into d_ws (100 x 16384 x 256 bits = 52.4 MB).
// Phase 2: persistent-state fused kernel: per t, h = Z(t) @ W^T via f16
//          split-2 MFMA (W = Whi + 2^-11 * Wlo', exact 0/1 A operand),
//          then bit-exact-vs-numpy LIF update (no FMA contraction), spike
//          count accumulated in registers; epilogue does the readout GEMM
//          via shfl reduction + atomicAdd.
//
// R2 change: k-loops were fully unrolled -> scheduler hoisted up to 32
// ds_read_b128 (128 VGPRs of Bf) -> ~80 regs/thread spilled -> 7.4 GB of
// scratch HBM traffic (measured R1: FETCH 4.99 GB + WRITE 2.39 GB, 46% of
// HBM peak, MfmaUtil 8.7%). Fix: #pragma unroll 2 on k-loops (8 Bf live),
// explicit acc zero-init. Peak live set ~200 VGPR < 256 cap at 2 waves/EU.

#define BB 16384
#define FF 256
#define HH 256
#define CC 10
#define TT 100

typedef __attribute__((ext_vector_type(8))) _Float16 half8;
typedef __attribute__((ext_vector_type(4))) float f32x4;

// ---------------- kernel 1: layer-1 spike bitmask ----------------
// wave = (b, 64-wide f segment); __ballot packs 64 spikes/step.
__global__ void spike_gen(const float* __restrict__ x,
                          unsigned long long* __restrict__ Z) {
  const int gw   = (int)((blockIdx.x * blockDim.x + threadIdx.x) >> 6);
  const int lane = threadIdx.x & 63;
  const int b    = gw >> 2;
  const int seg  = gw & 3;
  const float K_VM = (float)(0.001 * 100.0);        // 0.1f, numpy-exact
  const float K_ID = (float)(1.0 - 0.001 * 200.0);  // 0.8f, numpy-exact
  const float xv = x[b * FF + seg * 64 + lane];
  float v = 0.0f, cur = 0.0f;
  unsigned long long* zp = Z + (size_t)b * 4 + seg;
  for (int t = 0; t < TT; ++t) {
    // v_dec = v + 0.1f*((0-v)+i); i_dec = i*0.8f;  (separate roundings!)
    float vd   = __fadd_rn(v, __fmul_rn(K_VM, __fadd_rn(-v, cur)));
    float idec = __fmul_rn(cur, K_ID);
    bool z = (vd > 1.0f);  // == (vd - 1.0f) > 0
    unsigned long long m = __ballot(z);
    if (lane == 0) zp[(size_t)t * (BB * 4)] = m;
    v = z ? 0.0f : vd;
    cur = __fadd_rn(idec, xv);
  }
}

// unpack 8 spike bits -> 8 f16 values (0.0 / 1.0), MFMA fragment order
__device__ __forceinline__ half8 unpack_byte_f16(uint32_t byte) {
  union { uint32_t u[4]; half8 h; } r;
#pragma unroll
  for (int p = 0; p < 4; ++p) {
    uint32_t b2 = (byte >> (2 * p)) & 3u;
    // b2*0x8001 & 0x10001 puts bit0->bit0, bit1->bit16; *0x3C00 -> f16 1.0s
    r.u[p] = ((b2 * 0x8001u) & 0x10001u) * 0x3C00u;
  }
  return r.h;
}

// ---------------- kernel 2: fused temporal loop ----------------
// grid: (B/64) b-chunks x 4 h-chunks. block=256 (4 waves).
// wave tile: 16 b-rows x 64 h-cols, 4 timestep-planes per group.
__global__ __launch_bounds__(256, 2) void snn_main(
    const uint32_t* __restrict__ Z, const float* __restrict__ Wh,
    const float* __restrict__ bh, const float* __restrict__ Wr,
    const float* __restrict__ br, float* __restrict__ out) {
  // padded LDS copies of W rows (this block's 64 h) in split-f16
  __shared__ __align__(16) _Float16 WhiS[64][264];
  __shared__ __align__(16) _Float16 WloS[64][264];

  const int tid = threadIdx.x;
  const int bx  = blockIdx.x;
  const int hc  = bx & 3;
  const int bc  = bx >> 2;
  const int h0  = hc * 64;
  const int b0  = bc * 64;

  // ---- stage W -> LDS as (hi, lo*2048) f16 digits, denormal-guarded ----
  {
    const int r  = tid >> 2;         // 0..63 row
    const int f0 = (tid & 3) * 64;   // f segment
    const float* wrow = Wh + (size_t)(h0 + r) * FF + f0;
#pragma unroll 8
    for (int j = 0; j < 64; ++j) {
      float w = wrow[j];
      _Float16 hi = (fabsf(w) < 6.2e-5f) ? (_Float16)0.0f : (_Float16)w;
      _Float16 lo = (_Float16)((w - (float)hi) * 2048.0f);
      WhiS[r][f0 + j] = hi;
      WloS[r][f0 + j] = lo;
    }
  }
  __syncthreads();

  const int lane = tid & 63;
  const int wv   = tid >> 6;       // wave 0..3 -> b sub-tile
  const int col  = lane & 15;      // A: m-row / B: n-col / C: col
  const int quad = lane >> 4;      // k-chunk selector
  const int q8   = quad * 8;

  const int brow = b0 + wv * 16 + col;  // A-operand b row for this lane

  const float K_VM = (float)(0.001 * 100.0);
  const float K_ID = (float)(1.0 - 0.001 * 200.0);

  float v2[4][4], ii[4][4], sc[4][4];
#pragma unroll
  for (int nt = 0; nt < 4; ++nt)
#pragma unroll
    for (int r = 0; r < 4; ++r) { v2[nt][r] = 0.f; ii[nt][r] = 0.f; sc[nt][r] = 0.f; }

  float bias[4];
#pragma unroll
  for (int nt = 0; nt < 4; ++nt) bias[nt] = bh[h0 + nt * 16 + col];

#pragma unroll 1
  for (int tg = 0; tg < TT / 4; ++tg) {
    // preload spike bits: 4 t-planes x 32B row per lane
    uint32_t zb[4][8];
#pragma unroll
    for (int j = 0; j < 4; ++j) {
      const uint32_t* p = Z + ((size_t)(tg * 4 + j) * BB + brow) * 8;
      uint4 a = *(const uint4*)p;
      uint4 bq = *(const uint4*)(p + 4);
      zb[j][0] = a.x; zb[j][1] = a.y; zb[j][2] = a.z; zb[j][3] = a.w;
      zb[j][4] = bq.x; zb[j][5] = bq.y; zb[j][6] = bq.z; zb[j][7] = bq.w;
    }

    f32x4 acc[4][4];
#pragma unroll
    for (int j = 0; j < 4; ++j)
#pragma unroll
      for (int nt = 0; nt < 4; ++nt)
        acc[j][nt] = (f32x4){0.f, 0.f, 0.f, 0.f};

    // ---- phase LO: acc = Z . Wlo' ----
    // unroll 2 (not full): keeps only 8 Bf fragments live -> no spill
#pragma unroll 2
    for (int k = 0; k < 8; ++k) {
      half8 Bf[4];
#pragma unroll
      for (int nt = 0; nt < 4; ++nt)
        Bf[nt] = *(const half8*)&WloS[nt * 16 + col][k * 32 + q8];
#pragma unroll
      for (int j = 0; j < 4; ++j) {
        half8 Af = unpack_byte_f16((zb[j][k] >> q8) & 0xFFu);
#pragma unroll
        for (int nt = 0; nt < 4; ++nt) {
          acc[j][nt] = __builtin_amdgcn_mfma_f32_16x16x32_f16(
              Af, Bf[nt], acc[j][nt], 0, 0, 0);
        }
      }
    }
    // exact power-of-2 rescale of lo digit
#pragma unroll
    for (int j = 0; j < 4; ++j)
#pragma unroll
      for (int nt = 0; nt < 4; ++nt)
#pragma unroll
        for (int r = 0; r < 4; ++r)
          acc[j][nt][r] = __fmul_rn(acc[j][nt][r], 4.8828125e-4f); // 2^-11

    // ---- phase HI: acc += Z . Whi ----
#pragma unroll 2
    for (int k = 0; k < 8; ++k) {
      half8 Bf[4];
#pragma unroll
      for (int nt = 0; nt < 4; ++nt)
        Bf[nt] = *(const half8*)&WhiS[nt * 16 + col][k * 32 + q8];
#pragma unroll
      for (int j = 0; j < 4; ++j) {
        half8 Af = unpack_byte_f16((zb[j][k] >> q8) & 0xFFu);
#pragma unroll
        for (int nt = 0; nt < 4; ++nt) {
          acc[j][nt] = __builtin_amdgcn_mfma_f32_16x16x32_f16(
              Af, Bf[nt], acc[j][nt], 0, 0, 0);
        }
      }
    }

    // ---- 4 sequential layer-2 LIF updates (numpy op order) ----
#pragma unroll
    for (int j = 0; j < 4; ++j) {
#pragma unroll
      for (int nt = 0; nt < 4; ++nt) {
#pragma unroll
        for (int r = 0; r < 4; ++r) {
          float h  = __fadd_rn(acc[j][nt][r], bias[nt]);
          float vv = v2[nt][r], ci = ii[nt][r];
          float vd   = __fadd_rn(vv, __fmul_rn(K_VM, __fadd_rn(-vv, ci)));
          float idec = __fmul_rn(ci, K_ID);
          bool z = (vd > 1.0f);
          v2[nt][r] = z ? 0.0f : vd;
          ii[nt][r] = __fadd_rn(idec, h);
          sc[nt][r] = __fadd_rn(sc[nt][r], z ? 1.0f : 0.0f);
        }
      }
    }
  }

  // ---- epilogue: readout GEMM, fused ----
  float mean[4][4];
#pragma unroll
  for (int nt = 0; nt < 4; ++nt)
#pragma unroll
    for (int r = 0; r < 4; ++r) mean[nt][r] = __fdiv_rn(sc[nt][r], 100.0f);

#pragma unroll 1
  for (int c = 0; c < CC; ++c) {
    float wc[4];
#pragma unroll
    for (int nt = 0; nt < 4; ++nt) wc[nt] = Wr[c * HH + h0 + nt * 16 + col];
#pragma unroll
    for (int r = 0; r < 4; ++r) {
      float s = 0.f;
#pragma unroll
      for (int nt = 0; nt < 4; ++nt) s = fmaf(mean[nt][r], wc[nt], s);
      s += __shfl_xor(s, 1);
      s += __shfl_xor(s, 2);
      s += __shfl_xor(s, 4);
      s += __shfl_xor(s, 8);
      if (col == 0) {
        int b = b0 + wv * 16 + quad * 4 + r;
        float add = s + ((hc == 0) ? br[c] : 0.0f);
        atomicAdd(&out[b * CC + c], add);
      }
    }
  }
}

extern "C" void kernel_launch(void* const* d_in, const int* in_sizes, int n_in,
                              void* d_out, int out_size, void* d_ws, size_t ws_size,
                              hipStream_t stream) {
  const float* x  = (const float*)d_in[0];
  const float* Wh = (const float*)d_in[1];
  const float* bh = (const float*)d_in[2];
  const float* Wr = (const float*)d_in[3];
  const float* br = (const float*)d_in[4];
  float* out = (float*)d_out;

  // workspace: spike bitmask, 100*16384*32B = 52.4 MB
  unsigned long long* Z = (unsigned long long*)d_ws;

  hipMemsetAsync(d_out, 0, (size_t)out_size * sizeof(float), stream);
  spike_gen<<<BB, 256, 0, stream>>>(x, Z);
  snn_main<<<(BB / 64) * 4, 256, 0, stream>>>((const uint32_t*)Z, Wh, bh, Wr, br, out);
}

// Round 3
// 599.858 us; speedup vs baseline: 3.3245x; 1.1501x over previous
//
#include <hip/hip_runtime.h>
#include <hip/hip_fp16.h>
#include <stdint.h>

// SNNClassifier: B=16384, F=256, H=256, C=10, T=100
// Phase 1: layer-1 LIF spikes depend only on x[b,f] -> precompute 100-step
//          spike bitmask into d_ws (100 x 16384 x 256 bits = 52.4 MB).
//          R3: wave owns 16 (b,seg) states -> lanes 0..15 store 128B
//          contiguous per t (R2 version did 8B scattered stores -> ~180us).
// Phase 2: persistent-state fused kernel: per t, h = Z(t) @ W^T via f16
//          split-2 MFMA (W = Whi + 2^-11 * Wlo', exact 0/1 A operand),
//          then bit-exact-vs-numpy LIF update, spike count in registers;
//          epilogue does readout GEMM via shfl reduction + atomicAdd.
//
// R3 change in snn_main: R2's "#pragma unroll 2" made k runtime -> every
// zb[j][k] access became a dynamic VGPR select + per-access address v_mad
// (VALUBusy 74%, ~2.5x the source-level VALU count). Restore full unroll
// (compile-time k) and cap ds_read hoisting (R1's spill cause) with
// sched_barrier(0) every 2 k-steps + at phase boundaries. Peak live set
// ~acc64 + Bf32 + zb32 + state48 + misc ~= 220 VGPR < 256 @ 2 waves/EU.

#define BB 16384
#define FF 256
#define HH 256
#define CC 10
#define TT 100

typedef __attribute__((ext_vector_type(8))) _Float16 half8;
typedef __attribute__((ext_vector_type(4))) float f32x4;

// ---------------- kernel 1: layer-1 spike bitmask ----------------
// Block = 256 thr = 4 waves; wave owns 4 b-values x 4 segs (16 LIF states
// per thread). Ballot (jb,js) collected by lane jb*4+js; per t, lanes 0..15
// store 16 u64 = 128B contiguous; 4 waves cover 512B of the Z[t] row.
__global__ __launch_bounds__(256) void spike_gen(
    const float* __restrict__ x, unsigned long long* __restrict__ Z) {
  const int lane = threadIdx.x & 63;
  const int wv   = threadIdx.x >> 6;
  const int b0   = blockIdx.x * 16 + wv * 4;  // this wave's 4 b-values
  const float K_VM = (float)(0.001 * 100.0);        // 0.1f, numpy-exact
  const float K_ID = (float)(1.0 - 0.001 * 200.0);  // 0.8f, numpy-exact

  float v[16], cur[16], xv[16];
#pragma unroll
  for (int jb = 0; jb < 4; ++jb)
#pragma unroll
    for (int js = 0; js < 4; ++js) {
      const int idx = jb * 4 + js;
      xv[idx] = x[(size_t)(b0 + jb) * FF + js * 64 + lane];
      v[idx] = 0.0f; cur[idx] = 0.0f;
    }

  unsigned long long mymask = 0;
  unsigned long long* zp = Z + (size_t)b0 * 4;  // row slot base (u64 units)

  for (int t = 0; t < TT; ++t) {
#pragma unroll
    for (int idx = 0; idx < 16; ++idx) {
      float vd   = __fadd_rn(v[idx], __fmul_rn(K_VM, __fadd_rn(-v[idx], cur[idx])));
      float idec = __fmul_rn(cur[idx], K_ID);
      bool z = (vd > 1.0f);
      unsigned long long m = __ballot(z);
      if (lane == idx) mymask = m;  // lane idx owns slot (b0+jb)*4+js
      v[idx]   = z ? 0.0f : vd;
      cur[idx] = __fadd_rn(idec, xv[idx]);
    }
    if (lane < 16) zp[(size_t)t * (BB * 4) + lane] = mymask;
  }
}

// unpack 8 spike bits -> 8 f16 values (0.0 / 1.0), MFMA fragment order
__device__ __forceinline__ half8 unpack_byte_f16(uint32_t byte) {
  union { uint32_t u[4]; half8 h; } r;
#pragma unroll
  for (int p = 0; p < 4; ++p) {
    uint32_t b2 = (byte >> (2 * p)) & 3u;
    // b2*0x8001 & 0x10001 puts bit0->bit0, bit1->bit16; *0x3C00 -> f16 1.0s
    r.u[p] = ((b2 * 0x8001u) & 0x10001u) * 0x3C00u;
  }
  return r.h;
}

// ---------------- kernel 2: fused temporal loop ----------------
// grid: (B/64) b-chunks x 4 h-chunks. block=256 (4 waves).
// wave tile: 16 b-rows x 64 h-cols, 4 timestep-planes per group.
__global__ __launch_bounds__(256, 2) void snn_main(
    const uint32_t* __restrict__ Z, const float* __restrict__ Wh,
    const float* __restrict__ bh, const float* __restrict__ Wr,
    const float* __restrict__ br, float* __restrict__ out) {
  // padded LDS copies of W rows (this block's 64 h) in split-f16
  __shared__ __align__(16) _Float16 WhiS[64][264];
  __shared__ __align__(16) _Float16 WloS[64][264];

  const int tid = threadIdx.x;
  const int bx  = blockIdx.x;
  const int hc  = bx & 3;
  const int bc  = bx >> 2;
  const int h0  = hc * 64;
  const int b0  = bc * 64;

  // ---- stage W -> LDS as (hi, lo*2048) f16 digits, denormal-guarded ----
  {
    const int r  = tid >> 2;         // 0..63 row
    const int f0 = (tid & 3) * 64;   // f segment
    const float* wrow = Wh + (size_t)(h0 + r) * FF + f0;
#pragma unroll 8
    for (int j = 0; j < 64; ++j) {
      float w = wrow[j];
      _Float16 hi = (fabsf(w) < 6.2e-5f) ? (_Float16)0.0f : (_Float16)w;
      _Float16 lo = (_Float16)((w - (float)hi) * 2048.0f);
      WhiS[r][f0 + j] = hi;
      WloS[r][f0 + j] = lo;
    }
  }
  __syncthreads();

  const int lane = tid & 63;
  const int wv   = tid >> 6;       // wave 0..3 -> b sub-tile
  const int col  = lane & 15;      // A: m-row / B: n-col / C: col
  const int quad = lane >> 4;      // k-chunk selector
  const int q8   = quad * 8;

  const int brow = b0 + wv * 16 + col;  // A-operand b row for this lane

  const float K_VM = (float)(0.001 * 100.0);
  const float K_ID = (float)(1.0 - 0.001 * 200.0);

  float v2[4][4], ii[4][4], sc[4][4];
#pragma unroll
  for (int nt = 0; nt < 4; ++nt)
#pragma unroll
    for (int r = 0; r < 4; ++r) { v2[nt][r] = 0.f; ii[nt][r] = 0.f; sc[nt][r] = 0.f; }

  float bias[4];
#pragma unroll
  for (int nt = 0; nt < 4; ++nt) bias[nt] = bh[h0 + nt * 16 + col];

#pragma unroll 1
  for (int tg = 0; tg < TT / 4; ++tg) {
    // preload spike bits: 4 t-planes x 32B row per lane
    uint32_t zb[4][8];
#pragma unroll
    for (int j = 0; j < 4; ++j) {
      const uint32_t* p = Z + ((size_t)(tg * 4 + j) * BB + brow) * 8;
      uint4 a = *(const uint4*)p;
      uint4 bq = *(const uint4*)(p + 4);
      zb[j][0] = a.x; zb[j][1] = a.y; zb[j][2] = a.z; zb[j][3] = a.w;
      zb[j][4] = bq.x; zb[j][5] = bq.y; zb[j][6] = bq.z; zb[j][7] = bq.w;
    }

    f32x4 acc[4][4];
#pragma unroll
    for (int j = 0; j < 4; ++j)
#pragma unroll
      for (int nt = 0; nt < 4; ++nt)
        acc[j][nt] = (f32x4){0.f, 0.f, 0.f, 0.f};

    // ---- phase LO: acc = Z . Wlo' ----
    // full unroll (compile-time k -> static zb indexing / static LDS addrs);
    // sched_barrier every 2 k caps hoisted Bf fragments at 8 (no spill).
#pragma unroll
    for (int k = 0; k < 8; ++k) {
      half8 Bf[4];
#pragma unroll
      for (int nt = 0; nt < 4; ++nt)
        Bf[nt] = *(const half8*)&WloS[nt * 16 + col][k * 32 + q8];
#pragma unroll
      for (int j = 0; j < 4; ++j) {
        half8 Af = unpack_byte_f16((zb[j][k] >> q8) & 0xFFu);
#pragma unroll
        for (int nt = 0; nt < 4; ++nt) {
          acc[j][nt] = __builtin_amdgcn_mfma_f32_16x16x32_f16(
              Af, Bf[nt], acc[j][nt], 0, 0, 0);
        }
      }
      if (k & 1) __builtin_amdgcn_sched_barrier(0);
    }
    // exact power-of-2 rescale of lo digit
#pragma unroll
    for (int j = 0; j < 4; ++j)
#pragma unroll
      for (int nt = 0; nt < 4; ++nt)
#pragma unroll
        for (int r = 0; r < 4; ++r)
          acc[j][nt][r] = __fmul_rn(acc[j][nt][r], 4.8828125e-4f); // 2^-11
    __builtin_amdgcn_sched_barrier(0);

    // ---- phase HI: acc += Z . Whi ----
#pragma unroll
    for (int k = 0; k < 8; ++k) {
      half8 Bf[4];
#pragma unroll
      for (int nt = 0; nt < 4; ++nt)
        Bf[nt] = *(const half8*)&WhiS[nt * 16 + col][k * 32 + q8];
#pragma unroll
      for (int j = 0; j < 4; ++j) {
        half8 Af = unpack_byte_f16((zb[j][k] >> q8) & 0xFFu);
#pragma unroll
        for (int nt = 0; nt < 4; ++nt) {
          acc[j][nt] = __builtin_amdgcn_mfma_f32_16x16x32_f16(
              Af, Bf[nt], acc[j][nt], 0, 0, 0);
        }
      }
      if (k & 1) __builtin_amdgcn_sched_barrier(0);
    }

    // ---- 4 sequential layer-2 LIF updates (numpy op order) ----
#pragma unroll
    for (int j = 0; j < 4; ++j) {
#pragma unroll
      for (int nt = 0; nt < 4; ++nt) {
#pragma unroll
        for (int r = 0; r < 4; ++r) {
          float h  = __fadd_rn(acc[j][nt][r], bias[nt]);
          float vv = v2[nt][r], ci = ii[nt][r];
          float vd   = __fadd_rn(vv, __fmul_rn(K_VM, __fadd_rn(-vv, ci)));
          float idec = __fmul_rn(ci, K_ID);
          bool z = (vd > 1.0f);
          v2[nt][r] = z ? 0.0f : vd;
          ii[nt][r] = __fadd_rn(idec, h);
          sc[nt][r] = __fadd_rn(sc[nt][r], z ? 1.0f : 0.0f);
        }
      }
    }
  }

  // ---- epilogue: readout GEMM, fused ----
  float mean[4][4];
#pragma unroll
  for (int nt = 0; nt < 4; ++nt)
#pragma unroll
    for (int r = 0; r < 4; ++r) mean[nt][r] = __fdiv_rn(sc[nt][r], 100.0f);

#pragma unroll 1
  for (int c = 0; c < CC; ++c) {
    float wc[4];
#pragma unroll
    for (int nt = 0; nt < 4; ++nt) wc[nt] = Wr[c * HH + h0 + nt * 16 + col];
#pragma unroll
    for (int r = 0; r < 4; ++r) {
      float s = 0.f;
#pragma unroll
      for (int nt = 0; nt < 4; ++nt) s = fmaf(mean[nt][r], wc[nt], s);
      s += __shfl_xor(s, 1);
      s += __shfl_xor(s, 2);
      s += __shfl_xor(s, 4);
      s += __shfl_xor(s, 8);
      if (col == 0) {
        int b = b0 + wv * 16 + quad * 4 + r;
        float add = s + ((hc == 0) ? br[c] : 0.0f);
        atomicAdd(&out[b * CC + c], add);
      }
    }
  }
}

extern "C" void kernel_launch(void* const* d_in, const int* in_sizes, int n_in,
                              void* d_out, int out_size, void* d_ws, size_t ws_size,
                              hipStream_t stream) {
  const float* x  = (const float*)d_in[0];
  const float* Wh = (const float*)d_in[1];
  const float* bh = (const float*)d_in[2];
  const float* Wr = (const float*)d_in[3];
  const float* br = (const float*)d_in[4];
  float* out = (float*)d_out;

  // workspace: spike bitmask, 100*16384*32B = 52.4 MB
  unsigned long long* Z = (unsigned long long*)d_ws;

  hipMemsetAsync(d_out, 0, (size_t)out_size * sizeof(float), stream);
  spike_gen<<<BB / 16, 256, 0, stream>>>(x, Z);
  snn_main<<<(BB / 64) * 4, 256, 0, stream>>>((const uint32_t*)Z, Wh, bh, Wr, br, out);
}